// Round 4
// baseline (945.327 us; speedup 1.0000x reference)
//
#include <hip/hip_runtime.h>
#include <hip/hip_bf16.h>

#define N_NODES 100000
#define N_EDGES 1600000
#define D 128
#define N_LAYERS 4
#define LN_EPS 1e-5f
#define NB_SCAN ((N_NODES + 255) / 256)   // 391
#define BUCKET_SHIFT 7
#define NBUCKET ((N_NODES + 127) >> 7)    // 782
#define BCAP 4096

typedef _Float16 half8 __attribute__((ext_vector_type(8)));
typedef _Float16 half4v __attribute__((ext_vector_type(4)));
typedef float f32x4 __attribute__((ext_vector_type(4)));

// ---------------- CSR build ----------------
// pass 1: fused degree count + bucket partition (packed src|dst_local, 4B/edge)
__global__ void k_part(const int* __restrict__ ei, int* __restrict__ counts,
                       int* __restrict__ bcur, unsigned* __restrict__ bedge) {
    int e = blockIdx.x * blockDim.x + threadIdx.x;
    if (e < N_EDGES) {
        int src = ei[e];
        int dst = ei[N_EDGES + e];
        atomicAdd(&counts[dst], 1);
        int b = dst >> BUCKET_SHIFT;
        int p = atomicAdd(&bcur[b], 1);
        if (p < BCAP)
            bedge[(size_t)b * BCAP + p] = (unsigned)src | ((unsigned)(dst & 127) << 17);
    }
}

__global__ void k_dinv(const int* __restrict__ counts, float* __restrict__ dinv) {
    int i = blockIdx.x * blockDim.x + threadIdx.x;
    if (i < N_NODES) dinv[i] = rsqrtf((float)counts[i] + 1.0f);
}

__global__ __launch_bounds__(256) void k_scan1(const int* __restrict__ counts,
                                               int* __restrict__ row_start,
                                               int* __restrict__ blocksums) {
    __shared__ int buf[256];
    int tid = threadIdx.x;
    int i = blockIdx.x * 256 + tid;
    int c = (i < N_NODES) ? counts[i] : 0;
    buf[tid] = c;
    __syncthreads();
    #pragma unroll
    for (int off = 1; off < 256; off <<= 1) {
        int v = (tid >= off) ? buf[tid - off] : 0;
        __syncthreads();
        buf[tid] += v;
        __syncthreads();
    }
    if (i < N_NODES) row_start[i] = buf[tid] - c;
    if (tid == 255) blocksums[blockIdx.x] = buf[255];
}

__global__ __launch_bounds__(512) void k_scan2(const int* __restrict__ blocksums,
                                               int* __restrict__ blockoff) {
    __shared__ int buf[512];
    int tid = threadIdx.x;
    int c = (tid < NB_SCAN) ? blocksums[tid] : 0;
    buf[tid] = c;
    __syncthreads();
    #pragma unroll
    for (int off = 1; off < 512; off <<= 1) {
        int v = (tid >= off) ? buf[tid - off] : 0;
        __syncthreads();
        buf[tid] += v;
        __syncthreads();
    }
    if (tid < NB_SCAN) blockoff[tid] = buf[tid] - c;
}

__global__ __launch_bounds__(256) void k_scan3(const int* __restrict__ blockoff,
                                               int* __restrict__ row_start) {
    int i = blockIdx.x * 256 + threadIdx.x;
    if (i < N_NODES) row_start[i] += blockoff[blockIdx.x];
}

// pass 2: per-bucket CSR fill — LDS cursors, writes land in a contiguous ~16KB
// window per bucket so L2 merges lines (vs 1 line/edge for global scatter)
__global__ __launch_bounds__(256) void k_fillb(const unsigned* __restrict__ bedge,
                                               const int* __restrict__ bcur,
                                               const int* __restrict__ row_start,
                                               const float* __restrict__ dinv,
                                               uint2* __restrict__ colw) {
    __shared__ int cur[128];
    int b = blockIdx.x;
    int base = b << BUCKET_SHIFT;
    int t = threadIdx.x;
    if (t < 128) {
        int node = base + t;
        cur[t] = (node < N_NODES) ? row_start[node] : 0;
    }
    __syncthreads();
    int ecnt = min(bcur[b], BCAP);
    const unsigned* be = bedge + (size_t)b * BCAP;
    for (int j = t; j < ecnt; j += 256) {
        unsigned pe = be[j];
        int src = pe & 0x1FFFF;
        int dl  = pe >> 17;
        int p = atomicAdd(&cur[dl], 1);
        float wn = dinv[src] * dinv[base + dl];
        colw[p] = make_uint2((unsigned)src, __float_as_uint(wn));
    }
}

// ---------------- precision prep ----------------
__global__ __launch_bounds__(256) void k_cvt_x(const float* __restrict__ X,
                                               _Float16* __restrict__ H) {
    int i = blockIdx.x * 256 + threadIdx.x;
    if (i < N_NODES * D / 4) {
        float4 v = ((const float4*)X)[i];
        half4v o;
        o[0] = (_Float16)v.x; o[1] = (_Float16)v.y;
        o[2] = (_Float16)v.z; o[3] = (_Float16)v.w;
        ((half4v*)H)[i] = o;
    }
}

__global__ __launch_bounds__(256) void k_prep_w(const float* __restrict__ Ws,
                                                _Float16* __restrict__ WT) {
    int idx = blockIdx.x * 256 + threadIdx.x;
    int l = idx >> 14;
    int k = (idx >> 7) & 127;
    int n = idx & 127;
    WT[(size_t)l * D * D + (size_t)n * D + k] = (_Float16)Ws[(size_t)l * D * D + (size_t)k * D + n];
}

// ---------------- MFMA GEMM: HW = H @ W  (f16 in/out, f32 accum) ----------------
__global__ __launch_bounds__(256) void k_gemm(const _Float16* __restrict__ H,
                                              const _Float16* __restrict__ WT,
                                              _Float16* __restrict__ HW) {
    int t = threadIdx.x;
    int wave = t >> 6;
    int lane = t & 63;
    int wm = wave & 1, wn = wave >> 1;
    int m0 = blockIdx.x * 64 + wm * 32;
    int n0 = wn * 64;
    int lr = lane & 15;
    int kg = lane >> 4;

    f32x4 acc[2][4] = {};

    const half8* Hr[2];
    #pragma unroll
    for (int mi = 0; mi < 2; mi++) {
        int row = m0 + mi * 16 + lr;
        row = row < N_NODES ? row : N_NODES - 1;
        Hr[mi] = (const half8*)(H + (size_t)row * D);
    }
    const half8* Wr[4];
    #pragma unroll
    for (int ni = 0; ni < 4; ni++)
        Wr[ni] = (const half8*)(WT + (size_t)(n0 + ni * 16 + lr) * D);

    #pragma unroll
    for (int ks = 0; ks < 4; ks++) {
        half8 a0 = Hr[0][ks * 4 + kg];
        half8 a1 = Hr[1][ks * 4 + kg];
        half8 b0 = Wr[0][ks * 4 + kg];
        half8 b1 = Wr[1][ks * 4 + kg];
        half8 b2 = Wr[2][ks * 4 + kg];
        half8 b3 = Wr[3][ks * 4 + kg];
        acc[0][0] = __builtin_amdgcn_mfma_f32_16x16x32_f16(a0, b0, acc[0][0], 0, 0, 0);
        acc[0][1] = __builtin_amdgcn_mfma_f32_16x16x32_f16(a0, b1, acc[0][1], 0, 0, 0);
        acc[0][2] = __builtin_amdgcn_mfma_f32_16x16x32_f16(a0, b2, acc[0][2], 0, 0, 0);
        acc[0][3] = __builtin_amdgcn_mfma_f32_16x16x32_f16(a0, b3, acc[0][3], 0, 0, 0);
        acc[1][0] = __builtin_amdgcn_mfma_f32_16x16x32_f16(a1, b0, acc[1][0], 0, 0, 0);
        acc[1][1] = __builtin_amdgcn_mfma_f32_16x16x32_f16(a1, b1, acc[1][1], 0, 0, 0);
        acc[1][2] = __builtin_amdgcn_mfma_f32_16x16x32_f16(a1, b2, acc[1][2], 0, 0, 0);
        acc[1][3] = __builtin_amdgcn_mfma_f32_16x16x32_f16(a1, b3, acc[1][3], 0, 0, 0);
    }

    #pragma unroll
    for (int mi = 0; mi < 2; mi++) {
        #pragma unroll
        for (int r = 0; r < 4; r++) {
            int row = m0 + mi * 16 + kg * 4 + r;
            if (row < N_NODES) {
                _Float16* dst = HW + (size_t)row * D;
                #pragma unroll
                for (int ni = 0; ni < 4; ni++)
                    dst[n0 + ni * 16 + lr] = (_Float16)acc[mi][ni][r];
            }
        }
    }
}

// ------------- fused aggregation + self-loop + bias + LN + ReLU -------------
__global__ __launch_bounds__(256) void k_agg(const _Float16* __restrict__ HWh,
                                             const int* __restrict__ row_start,
                                             const int* __restrict__ counts,
                                             const uint2* __restrict__ colw,
                                             const float* __restrict__ dinv,
                                             const float* __restrict__ b,
                                             const float* __restrict__ gamma,
                                             const float* __restrict__ beta,
                                             _Float16* __restrict__ hout,
                                             float* __restrict__ fout,
                                             int last) {
    int half = threadIdx.x >> 5;
    int sl   = threadIdx.x & 31;
    int n = blockIdx.x * 8 + half;
    if (n >= N_NODES) return;

    int start = row_start[n];
    int cnt   = counts[n];
    const half4v* tbl = (const half4v*)HWh;
    const uint2* cw = colw + start;

    float a0 = 0.f, a1 = 0.f, a2 = 0.f, a3 = 0.f;
    int j = 0;
    for (; j + 2 <= cnt; j += 2) {
        uint2 e0 = cw[j];
        uint2 e1 = cw[j + 1];
        half4v v0 = tbl[(size_t)e0.x * 32 + sl];
        half4v v1 = tbl[(size_t)e1.x * 32 + sl];
        float w0 = __uint_as_float(e0.y);
        float w1 = __uint_as_float(e1.y);
        a0 += w0 * (float)v0[0] + w1 * (float)v1[0];
        a1 += w0 * (float)v0[1] + w1 * (float)v1[1];
        a2 += w0 * (float)v0[2] + w1 * (float)v1[2];
        a3 += w0 * (float)v0[3] + w1 * (float)v1[3];
    }
    if (j < cnt) {
        uint2 e0 = cw[j];
        half4v v0 = tbl[(size_t)e0.x * 32 + sl];
        float w0 = __uint_as_float(e0.y);
        a0 += w0 * (float)v0[0];
        a1 += w0 * (float)v0[1];
        a2 += w0 * (float)v0[2];
        a3 += w0 * (float)v0[3];
    }
    {   // self-loop
        float di = dinv[n];
        float w  = di * di;
        half4v v = tbl[(size_t)n * 32 + sl];
        a0 += w * (float)v[0];
        a1 += w * (float)v[1];
        a2 += w * (float)v[2];
        a3 += w * (float)v[3];
    }
    float4 bv = *(const float4*)(b + 4 * sl);
    a0 += bv.x; a1 += bv.y; a2 += bv.z; a3 += bv.w;

    float s = a0 + a1 + a2 + a3;
    #pragma unroll
    for (int off = 16; off >= 1; off >>= 1) s += __shfl_xor(s, off);
    float mean = s * (1.0f / 128.0f);
    float c0 = a0 - mean, c1 = a1 - mean, c2 = a2 - mean, c3 = a3 - mean;
    float q = c0 * c0 + c1 * c1 + c2 * c2 + c3 * c3;
    #pragma unroll
    for (int off = 16; off >= 1; off >>= 1) q += __shfl_xor(q, off);
    float rstd = rsqrtf(q * (1.0f / 128.0f) + LN_EPS);

    float4 gv = *(const float4*)(gamma + 4 * sl);
    float4 tv = *(const float4*)(beta  + 4 * sl);
    float o0 = fmaxf(c0 * rstd * gv.x + tv.x, 0.f);
    float o1 = fmaxf(c1 * rstd * gv.y + tv.y, 0.f);
    float o2 = fmaxf(c2 * rstd * gv.z + tv.z, 0.f);
    float o3 = fmaxf(c3 * rstd * gv.w + tv.w, 0.f);

    if (last) {
        ((float4*)(fout + (size_t)n * D))[sl] = make_float4(o0, o1, o2, o3);
    } else {
        half4v o;
        o[0] = (_Float16)o0; o[1] = (_Float16)o1;
        o[2] = (_Float16)o2; o[3] = (_Float16)o3;
        ((half4v*)(hout + (size_t)n * D))[sl] = o;
    }
}

extern "C" void kernel_launch(void* const* d_in, const int* in_sizes, int n_in,
                              void* d_out, int out_size, void* d_ws, size_t ws_size,
                              hipStream_t stream) {
    const float* x      = (const float*)d_in[0];
    const int*   ei     = (const int*)d_in[1];
    const float* Ws     = (const float*)d_in[2];
    const float* bs     = (const float*)d_in[3];
    const float* gammas = (const float*)d_in[4];
    const float* betas  = (const float*)d_in[5];
    float* out = (float*)d_out;

    char* ws = (char*)d_ws;
    int*   counts    = (int*)ws;   ws += (size_t)N_NODES * 4;
    int*   row_start = (int*)ws;   ws += (size_t)N_NODES * 4;
    float* dinv      = (float*)ws; ws += (size_t)N_NODES * 4;
    int*   blocksums = (int*)ws;   ws += 512 * 4;
    int*   blockoff  = (int*)ws;   ws += 512 * 4;
    int*   bcur      = (int*)ws;   ws += (size_t)NBUCKET * 4 + 64;
    unsigned* bedge  = (unsigned*)ws; ws += (size_t)NBUCKET * BCAP * 4;
    uint2* colw      = (uint2*)ws; ws += (size_t)N_EDGES * 8;
    _Float16* h      = (_Float16*)ws; ws += (size_t)N_NODES * D * 2;
    _Float16* hw     = (_Float16*)ws; ws += (size_t)N_NODES * D * 2;
    _Float16* wt     = (_Float16*)ws; ws += (size_t)N_LAYERS * D * D * 2;

    hipMemsetAsync(counts, 0, (size_t)N_NODES * 4, stream);
    hipMemsetAsync(bcur, 0, (size_t)NBUCKET * 4, stream);
    k_part<<<(N_EDGES + 255) / 256, 256, 0, stream>>>(ei, counts, bcur, bedge);
    k_dinv<<<(N_NODES + 255) / 256, 256, 0, stream>>>(counts, dinv);
    k_scan1<<<NB_SCAN, 256, 0, stream>>>(counts, row_start, blocksums);
    k_scan2<<<1, 512, 0, stream>>>(blocksums, blockoff);
    k_scan3<<<NB_SCAN, 256, 0, stream>>>(blockoff, row_start);
    k_fillb<<<NBUCKET, 256, 0, stream>>>(bedge, bcur, row_start, dinv, colw);
    k_cvt_x<<<(N_NODES * D / 4 + 255) / 256, 256, 0, stream>>>(x, h);
    k_prep_w<<<(N_LAYERS * D * D) / 256, 256, 0, stream>>>(Ws, wt);

    for (int l = 0; l < N_LAYERS; l++) {
        k_gemm<<<(N_NODES + 63) / 64, 256, 0, stream>>>(h, wt + (size_t)l * D * D, hw);
        int last = (l == N_LAYERS - 1) ? 1 : 0;
        k_agg<<<(N_NODES + 7) / 8, 256, 0, stream>>>(hw, row_start, counts, colw,
                                                     dinv, bs + l * D, gammas + l * D,
                                                     betas + l * D, h, out, last);
    }
}

// Round 5
// 534.942 us; speedup vs baseline: 1.7672x; 1.7672x over previous
//
#include <hip/hip_runtime.h>
#include <hip/hip_bf16.h>

#define N_NODES 100000
#define N_EDGES 1600000
#define D 128
#define N_LAYERS 4
#define LN_EPS 1e-5f
#define NB_SCAN ((N_NODES + 255) / 256)   // 391
#define NSLICE 8
#define NODES_PER_SLICE (N_NODES / NSLICE)  // 12500
#define FILL_CHUNKS 128
#define EDGES_PER_CHUNK (N_EDGES / FILL_CHUNKS)  // 12500

typedef _Float16 half8 __attribute__((ext_vector_type(8)));
typedef _Float16 half4v __attribute__((ext_vector_type(4)));
typedef float f32x4 __attribute__((ext_vector_type(4)));

// ---------------- CSR build ----------------
__global__ void k_count(const int* __restrict__ ei, int* __restrict__ counts) {
    int e = blockIdx.x * blockDim.x + threadIdx.x;
    if (e < N_EDGES) {
        int dst = ei[N_EDGES + e];
        atomicAdd(&counts[dst], 1);
    }
}

__global__ void k_dinv(const int* __restrict__ counts, float* __restrict__ dinv) {
    int i = blockIdx.x * blockDim.x + threadIdx.x;
    if (i < N_NODES) dinv[i] = rsqrtf((float)counts[i] + 1.0f);
}

__global__ __launch_bounds__(256) void k_scan1(const int* __restrict__ counts,
                                               int* __restrict__ row_start,
                                               int* __restrict__ blocksums) {
    __shared__ int buf[256];
    int tid = threadIdx.x;
    int i = blockIdx.x * 256 + tid;
    int c = (i < N_NODES) ? counts[i] : 0;
    buf[tid] = c;
    __syncthreads();
    #pragma unroll
    for (int off = 1; off < 256; off <<= 1) {
        int v = (tid >= off) ? buf[tid - off] : 0;
        __syncthreads();
        buf[tid] += v;
        __syncthreads();
    }
    if (i < N_NODES) row_start[i] = buf[tid] - c;
    if (tid == 255) blocksums[blockIdx.x] = buf[255];
}

__global__ __launch_bounds__(512) void k_scan2(const int* __restrict__ blocksums,
                                               int* __restrict__ blockoff) {
    __shared__ int buf[512];
    int tid = threadIdx.x;
    int c = (tid < NB_SCAN) ? blocksums[tid] : 0;
    buf[tid] = c;
    __syncthreads();
    #pragma unroll
    for (int off = 1; off < 512; off <<= 1) {
        int v = (tid >= off) ? buf[tid - off] : 0;
        __syncthreads();
        buf[tid] += v;
        __syncthreads();
    }
    if (tid < NB_SCAN) blockoff[tid] = buf[tid] - c;
}

__global__ __launch_bounds__(256) void k_scan3(const int* __restrict__ blockoff,
                                               int* __restrict__ row_start,
                                               int* __restrict__ cursor) {
    int i = blockIdx.x * 256 + threadIdx.x;
    if (i < N_NODES) {
        int rs = row_start[i] + blockoff[blockIdx.x];
        row_start[i] = rs;
        cursor[i] = rs;
    }
}

// XCD-sliced CSR fill: slice = blockIdx&7 rides the XCD round-robin, so each
// XCD only dirties its own 1/8 of col[] (0.8 MB, L2-resident) -> same-line
// writes coalesce in L2 instead of ping-ponging lines across XCDs.
__global__ __launch_bounds__(256) void k_fillx(const int* __restrict__ ei,
                                               int* __restrict__ cursor,
                                               int* __restrict__ col) {
    int wg = blockIdx.x;
    int slice = wg & (NSLICE - 1);
    int chunk = wg >> 3;
    int lo = slice * NODES_PER_SLICE;
    int hi = lo + NODES_PER_SLICE;
    int e0 = chunk * EDGES_PER_CHUNK;
    int e1 = e0 + EDGES_PER_CHUNK;
    for (int e = e0 + threadIdx.x; e < e1; e += 256) {
        int dst = ei[N_EDGES + e];
        if (dst >= lo && dst < hi) {
            int src = ei[e];
            int p = atomicAdd(&cursor[dst], 1);
            col[p] = src;
        }
    }
}

// ---------------- precision prep ----------------
__global__ __launch_bounds__(256) void k_cvt_x(const float* __restrict__ X,
                                               _Float16* __restrict__ H) {
    int i = blockIdx.x * 256 + threadIdx.x;
    if (i < N_NODES * D / 4) {
        float4 v = ((const float4*)X)[i];
        half4v o;
        o[0] = (_Float16)v.x; o[1] = (_Float16)v.y;
        o[2] = (_Float16)v.z; o[3] = (_Float16)v.w;
        ((half4v*)H)[i] = o;
    }
}

__global__ __launch_bounds__(256) void k_prep_w(const float* __restrict__ Ws,
                                                _Float16* __restrict__ WT) {
    int idx = blockIdx.x * 256 + threadIdx.x;
    int l = idx >> 14;
    int k = (idx >> 7) & 127;
    int n = idx & 127;
    WT[(size_t)l * D * D + (size_t)n * D + k] = (_Float16)Ws[(size_t)l * D * D + (size_t)k * D + n];
}

// -------- MFMA GEMM: HWs = dinv[row] * (H @ W)  (f16 in/out, f32 accum) --------
__global__ __launch_bounds__(256) void k_gemm(const _Float16* __restrict__ H,
                                              const _Float16* __restrict__ WT,
                                              const float* __restrict__ dinv,
                                              _Float16* __restrict__ HW) {
    int t = threadIdx.x;
    int wave = t >> 6;
    int lane = t & 63;
    int wm = wave & 1, wn = wave >> 1;
    int m0 = blockIdx.x * 64 + wm * 32;
    int n0 = wn * 64;
    int lr = lane & 15;
    int kg = lane >> 4;

    f32x4 acc[2][4] = {};

    const half8* Hr[2];
    #pragma unroll
    for (int mi = 0; mi < 2; mi++) {
        int row = m0 + mi * 16 + lr;
        row = row < N_NODES ? row : N_NODES - 1;
        Hr[mi] = (const half8*)(H + (size_t)row * D);
    }
    const half8* Wr[4];
    #pragma unroll
    for (int ni = 0; ni < 4; ni++)
        Wr[ni] = (const half8*)(WT + (size_t)(n0 + ni * 16 + lr) * D);

    #pragma unroll
    for (int ks = 0; ks < 4; ks++) {
        half8 a0 = Hr[0][ks * 4 + kg];
        half8 a1 = Hr[1][ks * 4 + kg];
        half8 b0 = Wr[0][ks * 4 + kg];
        half8 b1 = Wr[1][ks * 4 + kg];
        half8 b2 = Wr[2][ks * 4 + kg];
        half8 b3 = Wr[3][ks * 4 + kg];
        acc[0][0] = __builtin_amdgcn_mfma_f32_16x16x32_f16(a0, b0, acc[0][0], 0, 0, 0);
        acc[0][1] = __builtin_amdgcn_mfma_f32_16x16x32_f16(a0, b1, acc[0][1], 0, 0, 0);
        acc[0][2] = __builtin_amdgcn_mfma_f32_16x16x32_f16(a0, b2, acc[0][2], 0, 0, 0);
        acc[0][3] = __builtin_amdgcn_mfma_f32_16x16x32_f16(a0, b3, acc[0][3], 0, 0, 0);
        acc[1][0] = __builtin_amdgcn_mfma_f32_16x16x32_f16(a1, b0, acc[1][0], 0, 0, 0);
        acc[1][1] = __builtin_amdgcn_mfma_f32_16x16x32_f16(a1, b1, acc[1][1], 0, 0, 0);
        acc[1][2] = __builtin_amdgcn_mfma_f32_16x16x32_f16(a1, b2, acc[1][2], 0, 0, 0);
        acc[1][3] = __builtin_amdgcn_mfma_f32_16x16x32_f16(a1, b3, acc[1][3], 0, 0, 0);
    }

    #pragma unroll
    for (int mi = 0; mi < 2; mi++) {
        #pragma unroll
        for (int r = 0; r < 4; r++) {
            int row = m0 + mi * 16 + kg * 4 + r;
            if (row < N_NODES) {
                float dv = dinv[row];
                _Float16* dst = HW + (size_t)row * D;
                #pragma unroll
                for (int ni = 0; ni < 4; ni++)
                    dst[n0 + ni * 16 + lr] = (_Float16)(acc[mi][ni][r] * dv);
            }
        }
    }
}

// ------------- fused aggregation + self-loop + bias + LN + ReLU -------------
// agg[n] = dinv[n] * ( sum_{src in row} HWs[src] + HWs[n] ) + b   (HWs pre-scaled)
__global__ __launch_bounds__(256) void k_agg(const _Float16* __restrict__ HWs,
                                             const int* __restrict__ row_start,
                                             const int* __restrict__ counts,
                                             const int* __restrict__ col,
                                             const float* __restrict__ dinv,
                                             const float* __restrict__ b,
                                             const float* __restrict__ gamma,
                                             const float* __restrict__ beta,
                                             _Float16* __restrict__ hout,
                                             float* __restrict__ fout,
                                             int last) {
    int half = threadIdx.x >> 5;
    int sl   = threadIdx.x & 31;
    int n = blockIdx.x * 8 + half;
    if (n >= N_NODES) return;

    int start = row_start[n];
    int cnt   = counts[n];
    const half4v* tbl = (const half4v*)HWs;
    const int* cw = col + start;

    float a0 = 0.f, a1 = 0.f, a2 = 0.f, a3 = 0.f;
    int j = 0;
    for (; j + 4 <= cnt; j += 4) {
        int s0 = cw[j], s1 = cw[j + 1], s2 = cw[j + 2], s3 = cw[j + 3];
        half4v v0 = tbl[(size_t)s0 * 32 + sl];
        half4v v1 = tbl[(size_t)s1 * 32 + sl];
        half4v v2 = tbl[(size_t)s2 * 32 + sl];
        half4v v3 = tbl[(size_t)s3 * 32 + sl];
        a0 += (float)v0[0] + (float)v1[0] + (float)v2[0] + (float)v3[0];
        a1 += (float)v0[1] + (float)v1[1] + (float)v2[1] + (float)v3[1];
        a2 += (float)v0[2] + (float)v1[2] + (float)v2[2] + (float)v3[2];
        a3 += (float)v0[3] + (float)v1[3] + (float)v2[3] + (float)v3[3];
    }
    for (; j < cnt; j++) {
        int s0 = cw[j];
        half4v v0 = tbl[(size_t)s0 * 32 + sl];
        a0 += (float)v0[0]; a1 += (float)v0[1];
        a2 += (float)v0[2]; a3 += (float)v0[3];
    }
    {   // self-loop (HWs already carries one dinv factor)
        half4v v = tbl[(size_t)n * 32 + sl];
        a0 += (float)v[0]; a1 += (float)v[1];
        a2 += (float)v[2]; a3 += (float)v[3];
    }
    float dn = dinv[n];
    float4 bv = *(const float4*)(b + 4 * sl);
    a0 = a0 * dn + bv.x; a1 = a1 * dn + bv.y;
    a2 = a2 * dn + bv.z; a3 = a3 * dn + bv.w;

    float s = a0 + a1 + a2 + a3;
    #pragma unroll
    for (int off = 16; off >= 1; off >>= 1) s += __shfl_xor(s, off);
    float mean = s * (1.0f / 128.0f);
    float c0 = a0 - mean, c1 = a1 - mean, c2 = a2 - mean, c3 = a3 - mean;
    float q = c0 * c0 + c1 * c1 + c2 * c2 + c3 * c3;
    #pragma unroll
    for (int off = 16; off >= 1; off >>= 1) q += __shfl_xor(q, off);
    float rstd = rsqrtf(q * (1.0f / 128.0f) + LN_EPS);

    float4 gv = *(const float4*)(gamma + 4 * sl);
    float4 tv = *(const float4*)(beta  + 4 * sl);
    float o0 = fmaxf(c0 * rstd * gv.x + tv.x, 0.f);
    float o1 = fmaxf(c1 * rstd * gv.y + tv.y, 0.f);
    float o2 = fmaxf(c2 * rstd * gv.z + tv.z, 0.f);
    float o3 = fmaxf(c3 * rstd * gv.w + tv.w, 0.f);

    if (last) {
        ((float4*)(fout + (size_t)n * D))[sl] = make_float4(o0, o1, o2, o3);
    } else {
        half4v o;
        o[0] = (_Float16)o0; o[1] = (_Float16)o1;
        o[2] = (_Float16)o2; o[3] = (_Float16)o3;
        ((half4v*)(hout + (size_t)n * D))[sl] = o;
    }
}

extern "C" void kernel_launch(void* const* d_in, const int* in_sizes, int n_in,
                              void* d_out, int out_size, void* d_ws, size_t ws_size,
                              hipStream_t stream) {
    const float* x      = (const float*)d_in[0];
    const int*   ei     = (const int*)d_in[1];
    const float* Ws     = (const float*)d_in[2];
    const float* bs     = (const float*)d_in[3];
    const float* gammas = (const float*)d_in[4];
    const float* betas  = (const float*)d_in[5];
    float* out = (float*)d_out;

    char* ws = (char*)d_ws;
    int*   counts    = (int*)ws;   ws += (size_t)N_NODES * 4;
    int*   row_start = (int*)ws;   ws += (size_t)N_NODES * 4;
    int*   cursor    = (int*)ws;   ws += (size_t)N_NODES * 4;
    float* dinv      = (float*)ws; ws += (size_t)N_NODES * 4;
    int*   blocksums = (int*)ws;   ws += 512 * 4;
    int*   blockoff  = (int*)ws;   ws += 512 * 4;
    int*   col       = (int*)ws;   ws += (size_t)N_EDGES * 4;
    _Float16* h      = (_Float16*)ws; ws += (size_t)N_NODES * D * 2;
    _Float16* hw     = (_Float16*)ws; ws += (size_t)N_NODES * D * 2;
    _Float16* wt     = (_Float16*)ws; ws += (size_t)N_LAYERS * D * D * 2;

    hipMemsetAsync(counts, 0, (size_t)N_NODES * 4, stream);
    k_count<<<(N_EDGES + 255) / 256, 256, 0, stream>>>(ei, counts);
    k_dinv<<<(N_NODES + 255) / 256, 256, 0, stream>>>(counts, dinv);
    k_scan1<<<NB_SCAN, 256, 0, stream>>>(counts, row_start, blocksums);
    k_scan2<<<1, 512, 0, stream>>>(blocksums, blockoff);
    k_scan3<<<NB_SCAN, 256, 0, stream>>>(blockoff, row_start, cursor);
    k_fillx<<<NSLICE * FILL_CHUNKS, 256, 0, stream>>>(ei, cursor, col);
    k_cvt_x<<<(N_NODES * D / 4 + 255) / 256, 256, 0, stream>>>(x, h);
    k_prep_w<<<(N_LAYERS * D * D) / 256, 256, 0, stream>>>(Ws, wt);

    for (int l = 0; l < N_LAYERS; l++) {
        k_gemm<<<(N_NODES + 63) / 64, 256, 0, stream>>>(h, wt + (size_t)l * D * D, dinv, hw);
        int last = (l == N_LAYERS - 1) ? 1 : 0;
        k_agg<<<(N_NODES + 7) / 8, 256, 0, stream>>>(hw, row_start, counts, col,
                                                     dinv, bs + l * D, gammas + l * D,
                                                     betas + l * D, h, out, last);
    }
}

// Round 6
// 530.829 us; speedup vs baseline: 1.7809x; 1.0077x over previous
//
#include <hip/hip_runtime.h>
#include <hip/hip_bf16.h>

#define N_NODES 100000
#define N_EDGES 1600000
#define D 128
#define N_LAYERS 4
#define LN_EPS 1e-5f
#define NB_SCAN ((N_NODES + 255) / 256)   // 391
#define NSLICE 8
#define NODES_PER_SLICE (N_NODES / NSLICE)  // 12500
#define NCHUNK 128
#define CHUNK_E (N_EDGES / NCHUNK)          // 12500
#define SEG_CAP 2304                        // mean 1562, 19 sigma headroom

typedef _Float16 half8 __attribute__((ext_vector_type(8)));
typedef _Float16 half4v __attribute__((ext_vector_type(4)));
typedef float f32x4 __attribute__((ext_vector_type(4)));

// ---------------- CSR build ----------------
// phase A: one pass over ei. Fused degree count + partition edges into
// per-(chunk,slice) private segments. LDS cursors (8/WG) -> no global cursor
// contention (round-4 lesson); segment appends are dense sequential writes
// -> no partial-line writeback amplification (round-5 lesson).
__global__ __launch_bounds__(256) void k_partA(const int* __restrict__ ei,
                                               int* __restrict__ counts,
                                               unsigned* __restrict__ seg,
                                               int* __restrict__ segcnt) {
    __shared__ int lcnt[NSLICE];
    int w = blockIdx.x, t = threadIdx.x;
    if (t < NSLICE) lcnt[t] = 0;
    __syncthreads();
    int e0 = w * CHUNK_E;
    unsigned* myseg = seg + (size_t)w * NSLICE * SEG_CAP;
    for (int e = e0 + t; e < e0 + CHUNK_E; e += 256) {
        int src = ei[e];
        int dst = ei[N_EDGES + e];
        atomicAdd(&counts[dst], 1);
        int s  = dst / NODES_PER_SLICE;
        int dl = dst - s * NODES_PER_SLICE;          // < 16384 -> 14 bits
        int p = atomicAdd(&lcnt[s], 1);
        if (p < SEG_CAP)
            myseg[s * SEG_CAP + p] = (unsigned)src | ((unsigned)dl << 18);
    }
    __syncthreads();
    if (t < NSLICE) segcnt[w * NSLICE + t] = min(lcnt[t], SEG_CAP);
}

__global__ void k_dinv(const int* __restrict__ counts, float* __restrict__ dinv) {
    int i = blockIdx.x * blockDim.x + threadIdx.x;
    if (i < N_NODES) dinv[i] = rsqrtf((float)counts[i] + 1.0f);
}

__global__ __launch_bounds__(256) void k_scan1(const int* __restrict__ counts,
                                               int* __restrict__ row_start,
                                               int* __restrict__ blocksums) {
    __shared__ int buf[256];
    int tid = threadIdx.x;
    int i = blockIdx.x * 256 + tid;
    int c = (i < N_NODES) ? counts[i] : 0;
    buf[tid] = c;
    __syncthreads();
    #pragma unroll
    for (int off = 1; off < 256; off <<= 1) {
        int v = (tid >= off) ? buf[tid - off] : 0;
        __syncthreads();
        buf[tid] += v;
        __syncthreads();
    }
    if (i < N_NODES) row_start[i] = buf[tid] - c;
    if (tid == 255) blocksums[blockIdx.x] = buf[255];
}

__global__ __launch_bounds__(512) void k_scan2(const int* __restrict__ blocksums,
                                               int* __restrict__ blockoff) {
    __shared__ int buf[512];
    int tid = threadIdx.x;
    int c = (tid < NB_SCAN) ? blocksums[tid] : 0;
    buf[tid] = c;
    __syncthreads();
    #pragma unroll
    for (int off = 1; off < 512; off <<= 1) {
        int v = (tid >= off) ? buf[tid - off] : 0;
        __syncthreads();
        buf[tid] += v;
        __syncthreads();
    }
    if (tid < NB_SCAN) blockoff[tid] = buf[tid] - c;
}

__global__ __launch_bounds__(256) void k_scan3(const int* __restrict__ blockoff,
                                               int* __restrict__ row_start,
                                               int* __restrict__ cursor) {
    int i = blockIdx.x * 256 + threadIdx.x;
    if (i < N_NODES) {
        int rs = row_start[i] + blockoff[blockIdx.x];
        row_start[i] = rs;
        cursor[i] = rs;
    }
}

// phase B: slice = wg&7 rides the XCD round-robin; each slice's segment reads
// (~0.8MB) and col scatter window (~0.8MB) both live in that XCD's L2.
__global__ __launch_bounds__(256) void k_fillB(const unsigned* __restrict__ seg,
                                               const int* __restrict__ segcnt,
                                               int* __restrict__ cursor,
                                               int* __restrict__ col) {
    int w = blockIdx.x;            // 128 WGs
    int s = w & (NSLICE - 1);
    int part = w >> 3;             // 0..15 -> 8 chunks each
    int base = s * NODES_PER_SLICE;
    for (int c = part * 8; c < part * 8 + 8; c++) {
        const unsigned* sg = seg + ((size_t)c * NSLICE + s) * SEG_CAP;
        int cnt = segcnt[c * NSLICE + s];
        for (int j = threadIdx.x; j < cnt; j += 256) {
            unsigned pe = sg[j];
            int src = pe & 0x3FFFF;
            int dl  = pe >> 18;
            int p = atomicAdd(&cursor[base + dl], 1);
            col[p] = src;
        }
    }
}

// ---------------- precision prep ----------------
__global__ __launch_bounds__(256) void k_cvt_x(const float* __restrict__ X,
                                               _Float16* __restrict__ H) {
    int i = blockIdx.x * 256 + threadIdx.x;
    if (i < N_NODES * D / 4) {
        float4 v = ((const float4*)X)[i];
        half4v o;
        o[0] = (_Float16)v.x; o[1] = (_Float16)v.y;
        o[2] = (_Float16)v.z; o[3] = (_Float16)v.w;
        ((half4v*)H)[i] = o;
    }
}

__global__ __launch_bounds__(256) void k_prep_w(const float* __restrict__ Ws,
                                                _Float16* __restrict__ WT) {
    int idx = blockIdx.x * 256 + threadIdx.x;
    int l = idx >> 14;
    int k = (idx >> 7) & 127;
    int n = idx & 127;
    WT[(size_t)l * D * D + (size_t)n * D + k] = (_Float16)Ws[(size_t)l * D * D + (size_t)k * D + n];
}

// -------- MFMA GEMM: HWs = dinv[row] * (H @ W)  (f16 in/out, f32 accum) --------
__global__ __launch_bounds__(256) void k_gemm(const _Float16* __restrict__ H,
                                              const _Float16* __restrict__ WT,
                                              const float* __restrict__ dinv,
                                              _Float16* __restrict__ HW) {
    int t = threadIdx.x;
    int wave = t >> 6;
    int lane = t & 63;
    int wm = wave & 1, wn = wave >> 1;
    int m0 = blockIdx.x * 64 + wm * 32;
    int n0 = wn * 64;
    int lr = lane & 15;
    int kg = lane >> 4;

    f32x4 acc[2][4] = {};

    const half8* Hr[2];
    #pragma unroll
    for (int mi = 0; mi < 2; mi++) {
        int row = m0 + mi * 16 + lr;
        row = row < N_NODES ? row : N_NODES - 1;
        Hr[mi] = (const half8*)(H + (size_t)row * D);
    }
    const half8* Wr[4];
    #pragma unroll
    for (int ni = 0; ni < 4; ni++)
        Wr[ni] = (const half8*)(WT + (size_t)(n0 + ni * 16 + lr) * D);

    #pragma unroll
    for (int ks = 0; ks < 4; ks++) {
        half8 a0 = Hr[0][ks * 4 + kg];
        half8 a1 = Hr[1][ks * 4 + kg];
        half8 b0 = Wr[0][ks * 4 + kg];
        half8 b1 = Wr[1][ks * 4 + kg];
        half8 b2 = Wr[2][ks * 4 + kg];
        half8 b3 = Wr[3][ks * 4 + kg];
        acc[0][0] = __builtin_amdgcn_mfma_f32_16x16x32_f16(a0, b0, acc[0][0], 0, 0, 0);
        acc[0][1] = __builtin_amdgcn_mfma_f32_16x16x32_f16(a0, b1, acc[0][1], 0, 0, 0);
        acc[0][2] = __builtin_amdgcn_mfma_f32_16x16x32_f16(a0, b2, acc[0][2], 0, 0, 0);
        acc[0][3] = __builtin_amdgcn_mfma_f32_16x16x32_f16(a0, b3, acc[0][3], 0, 0, 0);
        acc[1][0] = __builtin_amdgcn_mfma_f32_16x16x32_f16(a1, b0, acc[1][0], 0, 0, 0);
        acc[1][1] = __builtin_amdgcn_mfma_f32_16x16x32_f16(a1, b1, acc[1][1], 0, 0, 0);
        acc[1][2] = __builtin_amdgcn_mfma_f32_16x16x32_f16(a1, b2, acc[1][2], 0, 0, 0);
        acc[1][3] = __builtin_amdgcn_mfma_f32_16x16x32_f16(a1, b3, acc[1][3], 0, 0, 0);
    }

    #pragma unroll
    for (int mi = 0; mi < 2; mi++) {
        #pragma unroll
        for (int r = 0; r < 4; r++) {
            int row = m0 + mi * 16 + kg * 4 + r;
            if (row < N_NODES) {
                float dv = dinv[row];
                _Float16* dst = HW + (size_t)row * D;
                #pragma unroll
                for (int ni = 0; ni < 4; ni++)
                    dst[n0 + ni * 16 + lr] = (_Float16)(acc[mi][ni][r] * dv);
            }
        }
    }
}

// ------------- fused aggregation + self-loop + bias + LN + ReLU -------------
// agg[n] = dinv[n] * ( sum_{src in row} HWs[src] + HWs[n] ) + b   (HWs pre-scaled)
__global__ __launch_bounds__(256) void k_agg(const _Float16* __restrict__ HWs,
                                             const int* __restrict__ row_start,
                                             const int* __restrict__ counts,
                                             const int* __restrict__ col,
                                             const float* __restrict__ dinv,
                                             const float* __restrict__ b,
                                             const float* __restrict__ gamma,
                                             const float* __restrict__ beta,
                                             _Float16* __restrict__ hout,
                                             float* __restrict__ fout,
                                             int last) {
    int half = threadIdx.x >> 5;
    int sl   = threadIdx.x & 31;
    int n = blockIdx.x * 8 + half;
    if (n >= N_NODES) return;

    int start = row_start[n];
    int cnt   = counts[n];
    const half4v* tbl = (const half4v*)HWs;
    const int* cw = col + start;

    float a0 = 0.f, a1 = 0.f, a2 = 0.f, a3 = 0.f;
    int j = 0;
    // 8-deep gather pipeline: indices first, then 8 outstanding row loads
    for (; j + 8 <= cnt; j += 8) {
        int sx[8];
        #pragma unroll
        for (int u = 0; u < 8; u++) sx[u] = cw[j + u];
        half4v vv[8];
        #pragma unroll
        for (int u = 0; u < 8; u++) vv[u] = tbl[(size_t)sx[u] * 32 + sl];
        #pragma unroll
        for (int u = 0; u < 8; u++) {
            a0 += (float)vv[u][0]; a1 += (float)vv[u][1];
            a2 += (float)vv[u][2]; a3 += (float)vv[u][3];
        }
    }
    for (; j + 2 <= cnt; j += 2) {
        int s0 = cw[j], s1 = cw[j + 1];
        half4v v0 = tbl[(size_t)s0 * 32 + sl];
        half4v v1 = tbl[(size_t)s1 * 32 + sl];
        a0 += (float)v0[0] + (float)v1[0];
        a1 += (float)v0[1] + (float)v1[1];
        a2 += (float)v0[2] + (float)v1[2];
        a3 += (float)v0[3] + (float)v1[3];
    }
    if (j < cnt) {
        int s0 = cw[j];
        half4v v0 = tbl[(size_t)s0 * 32 + sl];
        a0 += (float)v0[0]; a1 += (float)v0[1];
        a2 += (float)v0[2]; a3 += (float)v0[3];
    }
    {   // self-loop (HWs already carries one dinv factor)
        half4v v = tbl[(size_t)n * 32 + sl];
        a0 += (float)v[0]; a1 += (float)v[1];
        a2 += (float)v[2]; a3 += (float)v[3];
    }
    float dn = dinv[n];
    float4 bv = *(const float4*)(b + 4 * sl);
    a0 = a0 * dn + bv.x; a1 = a1 * dn + bv.y;
    a2 = a2 * dn + bv.z; a3 = a3 * dn + bv.w;

    float s = a0 + a1 + a2 + a3;
    #pragma unroll
    for (int off = 16; off >= 1; off >>= 1) s += __shfl_xor(s, off);
    float mean = s * (1.0f / 128.0f);
    float c0 = a0 - mean, c1 = a1 - mean, c2 = a2 - mean, c3 = a3 - mean;
    float q = c0 * c0 + c1 * c1 + c2 * c2 + c3 * c3;
    #pragma unroll
    for (int off = 16; off >= 1; off >>= 1) q += __shfl_xor(q, off);
    float rstd = rsqrtf(q * (1.0f / 128.0f) + LN_EPS);

    float4 gv = *(const float4*)(gamma + 4 * sl);
    float4 tv = *(const float4*)(beta  + 4 * sl);
    float o0 = fmaxf(c0 * rstd * gv.x + tv.x, 0.f);
    float o1 = fmaxf(c1 * rstd * gv.y + tv.y, 0.f);
    float o2 = fmaxf(c2 * rstd * gv.z + tv.z, 0.f);
    float o3 = fmaxf(c3 * rstd * gv.w + tv.w, 0.f);

    if (last) {
        ((float4*)(fout + (size_t)n * D))[sl] = make_float4(o0, o1, o2, o3);
    } else {
        half4v o;
        o[0] = (_Float16)o0; o[1] = (_Float16)o1;
        o[2] = (_Float16)o2; o[3] = (_Float16)o3;
        ((half4v*)(hout + (size_t)n * D))[sl] = o;
    }
}

extern "C" void kernel_launch(void* const* d_in, const int* in_sizes, int n_in,
                              void* d_out, int out_size, void* d_ws, size_t ws_size,
                              hipStream_t stream) {
    const float* x      = (const float*)d_in[0];
    const int*   ei     = (const int*)d_in[1];
    const float* Ws     = (const float*)d_in[2];
    const float* bs     = (const float*)d_in[3];
    const float* gammas = (const float*)d_in[4];
    const float* betas  = (const float*)d_in[5];
    float* out = (float*)d_out;

    char* ws = (char*)d_ws;
    int*   counts    = (int*)ws;   ws += (size_t)N_NODES * 4;
    int*   row_start = (int*)ws;   ws += (size_t)N_NODES * 4;
    int*   cursor    = (int*)ws;   ws += (size_t)N_NODES * 4;
    float* dinv      = (float*)ws; ws += (size_t)N_NODES * 4;
    int*   blocksums = (int*)ws;   ws += 512 * 4;
    int*   blockoff  = (int*)ws;   ws += 512 * 4;
    int*   segcnt    = (int*)ws;   ws += (size_t)NCHUNK * NSLICE * 4;
    unsigned* seg    = (unsigned*)ws; ws += (size_t)NCHUNK * NSLICE * SEG_CAP * 4;
    int*   col       = (int*)ws;   ws += (size_t)N_EDGES * 4;
    _Float16* h      = (_Float16*)ws; ws += (size_t)N_NODES * D * 2;
    _Float16* hw     = (_Float16*)ws; ws += (size_t)N_NODES * D * 2;
    _Float16* wt     = (_Float16*)ws; ws += (size_t)N_LAYERS * D * D * 2;

    hipMemsetAsync(counts, 0, (size_t)N_NODES * 4, stream);
    k_partA<<<NCHUNK, 256, 0, stream>>>(ei, counts, seg, segcnt);
    k_dinv<<<(N_NODES + 255) / 256, 256, 0, stream>>>(counts, dinv);
    k_scan1<<<NB_SCAN, 256, 0, stream>>>(counts, row_start, blocksums);
    k_scan2<<<1, 512, 0, stream>>>(blocksums, blockoff);
    k_scan3<<<NB_SCAN, 256, 0, stream>>>(blockoff, row_start, cursor);
    k_fillB<<<NCHUNK, 256, 0, stream>>>(seg, segcnt, cursor, col);
    k_cvt_x<<<(N_NODES * D / 4 + 255) / 256, 256, 0, stream>>>(x, h);
    k_prep_w<<<(N_LAYERS * D * D) / 256, 256, 0, stream>>>(Ws, wt);

    for (int l = 0; l < N_LAYERS; l++) {
        k_gemm<<<(N_NODES + 63) / 64, 256, 0, stream>>>(h, wt + (size_t)l * D * D, dinv, hw);
        int last = (l == N_LAYERS - 1) ? 1 : 0;
        k_agg<<<(N_NODES + 7) / 8, 256, 0, stream>>>(hw, row_start, counts, col,
                                                     dinv, bs + l * D, gammas + l * D,
                                                     betas + l * D, h, out, last);
    }
}

// Round 8
// 523.244 us; speedup vs baseline: 1.8067x; 1.0145x over previous
//
#include <hip/hip_runtime.h>
#include <hip/hip_bf16.h>

#define N_NODES 100000
#define N_EDGES 1600000
#define D 128
#define N_LAYERS 4
#define LN_EPS 1e-5f
#define NB_SCAN ((N_NODES + 255) / 256)   // 391
#define NSLICE 8
#define NODES_PER_SLICE (N_NODES / NSLICE)  // 12500
#define FILL_CHUNKS 128
#define EDGES_PER_CHUNK (N_EDGES / FILL_CHUNKS)  // 12500

typedef _Float16 half8 __attribute__((ext_vector_type(8)));
typedef _Float16 half4v __attribute__((ext_vector_type(4)));
typedef float f32x4 __attribute__((ext_vector_type(4)));

// ---------------- CSR build ----------------
__global__ void k_count(const int* __restrict__ ei, int* __restrict__ counts) {
    int e = blockIdx.x * blockDim.x + threadIdx.x;
    if (e < N_EDGES) {
        int dst = __builtin_nontemporal_load(ei + N_EDGES + e);
        atomicAdd(&counts[dst], 1);
    }
}

// scan phase 1 + fused dinv
__global__ __launch_bounds__(256) void k_scan1(const int* __restrict__ counts,
                                               int* __restrict__ row_start,
                                               int* __restrict__ blocksums,
                                               float* __restrict__ dinv) {
    __shared__ int buf[256];
    int tid = threadIdx.x;
    int i = blockIdx.x * 256 + tid;
    int c = (i < N_NODES) ? counts[i] : 0;
    if (i < N_NODES) dinv[i] = rsqrtf((float)c + 1.0f);
    buf[tid] = c;
    __syncthreads();
    #pragma unroll
    for (int off = 1; off < 256; off <<= 1) {
        int v = (tid >= off) ? buf[tid - off] : 0;
        __syncthreads();
        buf[tid] += v;
        __syncthreads();
    }
    if (i < N_NODES) row_start[i] = buf[tid] - c;
    if (tid == 255) blocksums[blockIdx.x] = buf[255];
}

__global__ __launch_bounds__(512) void k_scan2(const int* __restrict__ blocksums,
                                               int* __restrict__ blockoff) {
    __shared__ int buf[512];
    int tid = threadIdx.x;
    int c = (tid < NB_SCAN) ? blocksums[tid] : 0;
    buf[tid] = c;
    __syncthreads();
    #pragma unroll
    for (int off = 1; off < 512; off <<= 1) {
        int v = (tid >= off) ? buf[tid - off] : 0;
        __syncthreads();
        buf[tid] += v;
        __syncthreads();
    }
    if (tid < NB_SCAN) blockoff[tid] = buf[tid] - c;
}

__global__ __launch_bounds__(256) void k_scan3(const int* __restrict__ blockoff,
                                               int* __restrict__ row_start,
                                               int* __restrict__ cursor) {
    int i = blockIdx.x * 256 + threadIdx.x;
    if (i < N_NODES) {
        int rs = row_start[i] + blockoff[blockIdx.x];
        row_start[i] = rs;
        cursor[i] = rs;
    }
}

// XCD-sliced CSR fill. slice = blockIdx&7 rides the XCD round-robin, so each
// XCD only dirties its own 1/8 of col[] (0.8 MB, L2-resident). The ei stream
// is read NON-TEMPORALLY so it does not evict partially-filled col lines from
// L2 (round-5 lesson: the stream pollution caused 72 MB of writebacks).
__global__ __launch_bounds__(256) void k_fillx(const int* __restrict__ ei,
                                               int* __restrict__ cursor,
                                               int* __restrict__ col) {
    int wg = blockIdx.x;
    int slice = wg & (NSLICE - 1);
    int chunk = wg >> 3;
    int lo = slice * NODES_PER_SLICE;
    int hi = lo + NODES_PER_SLICE;
    int e0 = chunk * EDGES_PER_CHUNK;
    int e1 = e0 + EDGES_PER_CHUNK;
    for (int e = e0 + threadIdx.x; e < e1; e += 256) {
        int dst = __builtin_nontemporal_load(ei + N_EDGES + e);
        if (dst >= lo && dst < hi) {
            int src = __builtin_nontemporal_load(ei + e);
            int p = atomicAdd(&cursor[dst], 1);
            col[p] = src;
        }
    }
}

// ---------------- weight prep ----------------
__global__ __launch_bounds__(256) void k_prep_w(const float* __restrict__ Ws,
                                                _Float16* __restrict__ WT) {
    int idx = blockIdx.x * 256 + threadIdx.x;
    int l = idx >> 14;
    int k = (idx >> 7) & 127;
    int n = idx & 127;
    WT[(size_t)l * D * D + (size_t)n * D + k] = (_Float16)Ws[(size_t)l * D * D + (size_t)k * D + n];
}

// -------- MFMA GEMM: HWs = dinv[row] * (H @ W)  (f16 in, f16 out, f32 accum) ----
__global__ __launch_bounds__(256) void k_gemm(const _Float16* __restrict__ H,
                                              const _Float16* __restrict__ WT,
                                              const float* __restrict__ dinv,
                                              _Float16* __restrict__ HW) {
    int t = threadIdx.x;
    int wave = t >> 6;
    int lane = t & 63;
    int wm = wave & 1, wn = wave >> 1;
    int m0 = blockIdx.x * 64 + wm * 32;
    int n0 = wn * 64;
    int lr = lane & 15;
    int kg = lane >> 4;

    f32x4 acc[2][4] = {};

    const half8* Hr[2];
    #pragma unroll
    for (int mi = 0; mi < 2; mi++) {
        int row = m0 + mi * 16 + lr;
        row = row < N_NODES ? row : N_NODES - 1;
        Hr[mi] = (const half8*)(H + (size_t)row * D);
    }
    const half8* Wr[4];
    #pragma unroll
    for (int ni = 0; ni < 4; ni++)
        Wr[ni] = (const half8*)(WT + (size_t)(n0 + ni * 16 + lr) * D);

    #pragma unroll
    for (int ks = 0; ks < 4; ks++) {
        half8 a0 = Hr[0][ks * 4 + kg];
        half8 a1 = Hr[1][ks * 4 + kg];
        half8 b0 = Wr[0][ks * 4 + kg];
        half8 b1 = Wr[1][ks * 4 + kg];
        half8 b2 = Wr[2][ks * 4 + kg];
        half8 b3 = Wr[3][ks * 4 + kg];
        acc[0][0] = __builtin_amdgcn_mfma_f32_16x16x32_f16(a0, b0, acc[0][0], 0, 0, 0);
        acc[0][1] = __builtin_amdgcn_mfma_f32_16x16x32_f16(a0, b1, acc[0][1], 0, 0, 0);
        acc[0][2] = __builtin_amdgcn_mfma_f32_16x16x32_f16(a0, b2, acc[0][2], 0, 0, 0);
        acc[0][3] = __builtin_amdgcn_mfma_f32_16x16x32_f16(a0, b3, acc[0][3], 0, 0, 0);
        acc[1][0] = __builtin_amdgcn_mfma_f32_16x16x32_f16(a1, b0, acc[1][0], 0, 0, 0);
        acc[1][1] = __builtin_amdgcn_mfma_f32_16x16x32_f16(a1, b1, acc[1][1], 0, 0, 0);
        acc[1][2] = __builtin_amdgcn_mfma_f32_16x16x32_f16(a1, b2, acc[1][2], 0, 0, 0);
        acc[1][3] = __builtin_amdgcn_mfma_f32_16x16x32_f16(a1, b3, acc[1][3], 0, 0, 0);
    }

    #pragma unroll
    for (int mi = 0; mi < 2; mi++) {
        #pragma unroll
        for (int r = 0; r < 4; r++) {
            int row = m0 + mi * 16 + kg * 4 + r;
            if (row < N_NODES) {
                float dv = dinv[row];
                _Float16* dst = HW + (size_t)row * D;
                #pragma unroll
                for (int ni = 0; ni < 4; ni++)
                    dst[n0 + ni * 16 + lr] = (_Float16)(acc[mi][ni][r] * dv);
            }
        }
    }
}

// layer-0 variant: reads f32 x directly, converts in-register (kills k_cvt_x)
__global__ __launch_bounds__(256) void k_gemm0(const float* __restrict__ X,
                                               const _Float16* __restrict__ WT,
                                               const float* __restrict__ dinv,
                                               _Float16* __restrict__ HW) {
    int t = threadIdx.x;
    int wave = t >> 6;
    int lane = t & 63;
    int wm = wave & 1, wn = wave >> 1;
    int m0 = blockIdx.x * 64 + wm * 32;
    int n0 = wn * 64;
    int lr = lane & 15;
    int kg = lane >> 4;

    f32x4 acc[2][4] = {};

    const float4* Xr[2];
    #pragma unroll
    for (int mi = 0; mi < 2; mi++) {
        int row = m0 + mi * 16 + lr;
        row = row < N_NODES ? row : N_NODES - 1;
        Xr[mi] = (const float4*)(X + (size_t)row * D);
    }
    const half8* Wr[4];
    #pragma unroll
    for (int ni = 0; ni < 4; ni++)
        Wr[ni] = (const half8*)(WT + (size_t)(n0 + ni * 16 + lr) * D);

    #pragma unroll
    for (int ks = 0; ks < 4; ks++) {
        half8 a0, a1;
        {
            float4 p = Xr[0][(ks * 4 + kg) * 2];
            float4 q = Xr[0][(ks * 4 + kg) * 2 + 1];
            a0[0] = (_Float16)p.x; a0[1] = (_Float16)p.y; a0[2] = (_Float16)p.z; a0[3] = (_Float16)p.w;
            a0[4] = (_Float16)q.x; a0[5] = (_Float16)q.y; a0[6] = (_Float16)q.z; a0[7] = (_Float16)q.w;
            float4 r = Xr[1][(ks * 4 + kg) * 2];
            float4 s = Xr[1][(ks * 4 + kg) * 2 + 1];
            a1[0] = (_Float16)r.x; a1[1] = (_Float16)r.y; a1[2] = (_Float16)r.z; a1[3] = (_Float16)r.w;
            a1[4] = (_Float16)s.x; a1[5] = (_Float16)s.y; a1[6] = (_Float16)s.z; a1[7] = (_Float16)s.w;
        }
        half8 b0 = Wr[0][ks * 4 + kg];
        half8 b1 = Wr[1][ks * 4 + kg];
        half8 b2 = Wr[2][ks * 4 + kg];
        half8 b3 = Wr[3][ks * 4 + kg];
        acc[0][0] = __builtin_amdgcn_mfma_f32_16x16x32_f16(a0, b0, acc[0][0], 0, 0, 0);
        acc[0][1] = __builtin_amdgcn_mfma_f32_16x16x32_f16(a0, b1, acc[0][1], 0, 0, 0);
        acc[0][2] = __builtin_amdgcn_mfma_f32_16x16x32_f16(a0, b2, acc[0][2], 0, 0, 0);
        acc[0][3] = __builtin_amdgcn_mfma_f32_16x16x32_f16(a0, b3, acc[0][3], 0, 0, 0);
        acc[1][0] = __builtin_amdgcn_mfma_f32_16x16x32_f16(a1, b0, acc[1][0], 0, 0, 0);
        acc[1][1] = __builtin_amdgcn_mfma_f32_16x16x32_f16(a1, b1, acc[1][1], 0, 0, 0);
        acc[1][2] = __builtin_amdgcn_mfma_f32_16x16x32_f16(a1, b2, acc[1][2], 0, 0, 0);
        acc[1][3] = __builtin_amdgcn_mfma_f32_16x16x32_f16(a1, b3, acc[1][3], 0, 0, 0);
    }

    #pragma unroll
    for (int mi = 0; mi < 2; mi++) {
        #pragma unroll
        for (int r = 0; r < 4; r++) {
            int row = m0 + mi * 16 + kg * 4 + r;
            if (row < N_NODES) {
                float dv = dinv[row];
                _Float16* dst = HW + (size_t)row * D;
                #pragma unroll
                for (int ni = 0; ni < 4; ni++)
                    dst[n0 + ni * 16 + lr] = (_Float16)(acc[mi][ni][r] * dv);
            }
        }
    }
}

// ------------- fused aggregation + self-loop + bias + LN + ReLU -------------
__global__ __launch_bounds__(256) void k_agg(const _Float16* __restrict__ HWs,
                                             const int* __restrict__ row_start,
                                             const int* __restrict__ counts,
                                             const int* __restrict__ col,
                                             const float* __restrict__ dinv,
                                             const float* __restrict__ b,
                                             const float* __restrict__ gamma,
                                             const float* __restrict__ beta,
                                             _Float16* __restrict__ hout,
                                             float* __restrict__ fout,
                                             int last) {
    int half = threadIdx.x >> 5;
    int sl   = threadIdx.x & 31;
    int n = blockIdx.x * 8 + half;
    if (n >= N_NODES) return;

    int start = row_start[n];
    int cnt   = counts[n];
    const half4v* tbl = (const half4v*)HWs;
    const int* cw = col + start;

    float a0 = 0.f, a1 = 0.f, a2 = 0.f, a3 = 0.f;
    int j = 0;
    for (; j + 8 <= cnt; j += 8) {
        int sx[8];
        #pragma unroll
        for (int u = 0; u < 8; u++) sx[u] = cw[j + u];
        half4v vv[8];
        #pragma unroll
        for (int u = 0; u < 8; u++) vv[u] = tbl[(size_t)sx[u] * 32 + sl];
        #pragma unroll
        for (int u = 0; u < 8; u++) {
            a0 += (float)vv[u][0]; a1 += (float)vv[u][1];
            a2 += (float)vv[u][2]; a3 += (float)vv[u][3];
        }
    }
    for (; j + 2 <= cnt; j += 2) {
        int s0 = cw[j], s1 = cw[j + 1];
        half4v v0 = tbl[(size_t)s0 * 32 + sl];
        half4v v1 = tbl[(size_t)s1 * 32 + sl];
        a0 += (float)v0[0] + (float)v1[0];
        a1 += (float)v0[1] + (float)v1[1];
        a2 += (float)v0[2] + (float)v1[2];
        a3 += (float)v0[3] + (float)v1[3];
    }
    if (j < cnt) {
        int s0 = cw[j];
        half4v v0 = tbl[(size_t)s0 * 32 + sl];
        a0 += (float)v0[0]; a1 += (float)v0[1];
        a2 += (float)v0[2]; a3 += (float)v0[3];
    }
    {   // self-loop (HWs already carries one dinv factor)
        half4v v = tbl[(size_t)n * 32 + sl];
        a0 += (float)v[0]; a1 += (float)v[1];
        a2 += (float)v[2]; a3 += (float)v[3];
    }
    float dn = dinv[n];
    float4 bv = *(const float4*)(b + 4 * sl);
    a0 = a0 * dn + bv.x; a1 = a1 * dn + bv.y;
    a2 = a2 * dn + bv.z; a3 = a3 * dn + bv.w;

    float s = a0 + a1 + a2 + a3;
    #pragma unroll
    for (int off = 16; off >= 1; off >>= 1) s += __shfl_xor(s, off);
    float mean = s * (1.0f / 128.0f);
    float c0 = a0 - mean, c1 = a1 - mean, c2 = a2 - mean, c3 = a3 - mean;
    float q = c0 * c0 + c1 * c1 + c2 * c2 + c3 * c3;
    #pragma unroll
    for (int off = 16; off >= 1; off >>= 1) q += __shfl_xor(q, off);
    float rstd = rsqrtf(q * (1.0f / 128.0f) + LN_EPS);

    float4 gv = *(const float4*)(gamma + 4 * sl);
    float4 tv = *(const float4*)(beta  + 4 * sl);
    float o0 = fmaxf(c0 * rstd * gv.x + tv.x, 0.f);
    float o1 = fmaxf(c1 * rstd * gv.y + tv.y, 0.f);
    float o2 = fmaxf(c2 * rstd * gv.z + tv.z, 0.f);
    float o3 = fmaxf(c3 * rstd * gv.w + tv.w, 0.f);

    if (last) {
        f32x4 o4; o4[0] = o0; o4[1] = o1; o4[2] = o2; o4[3] = o3;
        __builtin_nontemporal_store(o4, (f32x4*)(fout + (size_t)n * D) + sl);
    } else {
        half4v o;
        o[0] = (_Float16)o0; o[1] = (_Float16)o1;
        o[2] = (_Float16)o2; o[3] = (_Float16)o3;
        ((half4v*)(hout + (size_t)n * D))[sl] = o;
    }
}

extern "C" void kernel_launch(void* const* d_in, const int* in_sizes, int n_in,
                              void* d_out, int out_size, void* d_ws, size_t ws_size,
                              hipStream_t stream) {
    const float* x      = (const float*)d_in[0];
    const int*   ei     = (const int*)d_in[1];
    const float* Ws     = (const float*)d_in[2];
    const float* bs     = (const float*)d_in[3];
    const float* gammas = (const float*)d_in[4];
    const float* betas  = (const float*)d_in[5];
    float* out = (float*)d_out;

    char* ws = (char*)d_ws;
    int*   counts    = (int*)ws;   ws += (size_t)N_NODES * 4;
    int*   row_start = (int*)ws;   ws += (size_t)N_NODES * 4;
    int*   cursor    = (int*)ws;   ws += (size_t)N_NODES * 4;
    float* dinv      = (float*)ws; ws += (size_t)N_NODES * 4;
    int*   blocksums = (int*)ws;   ws += 512 * 4;
    int*   blockoff  = (int*)ws;   ws += 512 * 4;
    int*   col       = (int*)ws;   ws += (size_t)N_EDGES * 4;
    _Float16* h      = (_Float16*)ws; ws += (size_t)N_NODES * D * 2;
    _Float16* hw     = (_Float16*)ws; ws += (size_t)N_NODES * D * 2;
    _Float16* wt     = (_Float16*)ws; ws += (size_t)N_LAYERS * D * D * 2;

    (void)hipMemsetAsync(counts, 0, (size_t)N_NODES * 4, stream);
    k_count<<<(N_EDGES + 255) / 256, 256, 0, stream>>>(ei, counts);
    k_scan1<<<NB_SCAN, 256, 0, stream>>>(counts, row_start, blocksums, dinv);
    k_scan2<<<1, 512, 0, stream>>>(blocksums, blockoff);
    k_scan3<<<NB_SCAN, 256, 0, stream>>>(blockoff, row_start, cursor);
    k_fillx<<<NSLICE * FILL_CHUNKS, 256, 0, stream>>>(ei, cursor, col);
    k_prep_w<<<(N_LAYERS * D * D) / 256, 256, 0, stream>>>(Ws, wt);

    for (int l = 0; l < N_LAYERS; l++) {
        if (l == 0)
            k_gemm0<<<(N_NODES + 63) / 64, 256, 0, stream>>>(x, wt, dinv, hw);
        else
            k_gemm<<<(N_NODES + 63) / 64, 256, 0, stream>>>(h, wt + (size_t)l * D * D, dinv, hw);
        int last = (l == N_LAYERS - 1) ? 1 : 0;
        k_agg<<<(N_NODES + 7) / 8, 256, 0, stream>>>(hw, row_start, counts, col,
                                                     dinv, bs + l * D, gammas + l * D,
                                                     betas + l * D, h, out, last);
    }
}